// Round 9
// baseline (227.759 us; speedup 1.0000x reference)
//
#include <hip/hip_runtime.h>
#include <hip/hip_bf16.h>

#define NB 16
#define SEQ 2048
#define EDIM 256

typedef __attribute__((ext_vector_type(16))) float f32x16;
typedef __attribute__((ext_vector_type(4)))  float f32x4;
typedef __attribute__((ext_vector_type(8)))  short short8;

static __device__ __forceinline__ ushort f2bf(float f) {
    uint32_t u = __float_as_uint(f);
    uint32_t r = (u + 0x7fffu + ((u >> 16) & 1u)) >> 16;
    return (ushort)r;
}
static __device__ __forceinline__ float bf2f(ushort h) {
    return __uint_as_float(((uint32_t)h) << 16);
}
// packed f32->bf16 (RNE)
static __device__ __forceinline__ uint32_t cvt_pk_bf16(float lo, float hi) {
    uint32_t r;
    asm("v_cvt_pk_bf16_f32 %0, %1, %2" : "=v"(r) : "v"(lo), "v"(hi));
    return r;
}
// async global->LDS, 16 bytes per lane; LDS dest wave-uniform, global src per-lane.
static __device__ __forceinline__ void gll16(const ushort* g, ushort* l) {
    __builtin_amdgcn_global_load_lds(
        (const __attribute__((address_space(1))) uint32_t*)g,
        (__attribute__((address_space(3))) uint32_t*)l,
        16, 0, 0);
}

// Kernel 1: fp32 -> bf16 in K-MAJOR PANEL layout xb[b][ks][t][j] (ks=e>>4,
// j=e&15), plus per-row sum of squares of the bf16-rounded values (distance
// diagonal cancels exactly against the fp32-accumulated MFMA gram).
__global__ void prep_kernel(const float* __restrict__ x,
                            ushort* __restrict__ xb,
                            float* __restrict__ sq) {
    __shared__ ushort sh[4][256];
    const int tid  = threadIdx.x;
    const int r    = tid >> 6;
    const int lane = tid & 63;
    const int grow = blockIdx.x * 4;
    const int row  = grow + r;

    const f32x4* xp = reinterpret_cast<const f32x4*>(x + (size_t)row * EDIM + lane * 4);
    const f32x4 v = __builtin_nontemporal_load(xp);
    ushort h0 = f2bf(v.x), h1 = f2bf(v.y), h2 = f2bf(v.z), h3 = f2bf(v.w);
    ushort4 h; h.x = h0; h.y = h1; h.z = h2; h.w = h3;
    *reinterpret_cast<ushort4*>(&sh[r][lane * 4]) = h;

    const float fx = bf2f(h0), fy = bf2f(h1), fz = bf2f(h2), fw = bf2f(h3);
    float s = fx * fx + fy * fy + fz * fz + fw * fw;
    #pragma unroll
    for (int m = 1; m < 64; m <<= 1) s += __shfl_xor(s, m);
    if (lane == 0) sq[row] = s;

    __syncthreads();

    const int b   = grow >> 11;
    const int t0  = grow & 2047;
    const int ksx = tid >> 4;
    const int idx = tid & 15;
    const int r2  = idx >> 2;
    const int j   = (idx & 3) * 4;
    ushort4 o = *reinterpret_cast<ushort4*>(&sh[r2][ksx * 16 + j]);
    *reinterpret_cast<ushort4*>(xb + (size_t)b * SEQ * EDIM
                                   + (size_t)ksx * SEQ * 16
                                   + (size_t)(t0 + r2) * 16 + j) = o;
}

// Kernel 2: fused gram-GEMM + one-pass softmax, PIPELINED over 4 row-blocks
// per WG. WG = 1024 thr (16 waves), 32 rows x full 2048 cols per row-block;
// wave w owns cols [w*128,(w+1)*128). grid (16,16) = exactly 1 WG/CU.
// Stores of row-block i (packed to bf16 pairs, 32 VGPR) are interleaved into
// the K-loop of row-block i+1 so the HBM write drain overlaps the L2-bound
// GEMM. Raw s_barrier + lgkmcnt-only waits (NO __syncthreads -> no vmcnt(0)
// drain of the in-flight nt stores).
__global__ __launch_bounds__(1024, 4) void sims_main(
        const ushort* __restrict__ xb,
        const float*  __restrict__ sq,
        float* __restrict__ out) {
    __shared__ __align__(16) ushort Ab[16 * 512];   // 16 KB: [ks][64 chunks][8]
    __shared__ float red[32][17];
    __shared__ float inv_s[32];

    const int b    = blockIdx.x;        // batch -> XCD = flat%8 = b%8
    const int rbg  = blockIdx.y;        // 0..15; rowblk = rbg*4 + rb
    const int tid  = threadIdx.x;
    const int wave = tid >> 6;          // 0..15
    const int lane = tid & 63;
    const int l31  = lane & 31;
    const int hi   = lane >> 5;

    const ushort* xbB = xb + (size_t)b * SEQ * EDIM;
    const float*  sqB = sq + b * SEQ;
    float* outB = out + (size_t)b * SEQ * SEQ;

    const int colw = wave * 128;
    const ushort* bbase = xbB + ((size_t)colw + l31) * 16 + hi * 8;
    const int gl  = lane ^ ((lane >> 3) & 7);       // A-stage src chunk swizzle
    const int r6  = l31 * 2 + hi;
    const int pr6 = r6 ^ ((r6 >> 3) & 7);           // swizzled A read chunk

    float sqc[4];
    #pragma unroll
    for (int cb = 0; cb < 4; ++cb) sqc[cb] = sqB[colw + cb * 32 + l31];

    constexpr float kC = (float)(-1.4426950408889634 / 13.544);  // -log2(e)/T

    uint32_t pk[4][8];                  // prev row-block, scaled, bf16-packed
    int prev_base = 0;

    #pragma unroll 1
    for (int rb = 0; rb < 4; ++rb) {
        const int row_base = (rbg * 4 + rb) * 32;

        // ---- restage A panel (waves all past K-loop: epilogue barriers) ----
        gll16(xbB + (size_t)wave * (SEQ * 16) + (row_base + (gl >> 1)) * 16 + (gl & 1) * 8,
              Ab + wave * 512);
        asm volatile("s_waitcnt vmcnt(0)" ::: "memory");
        __builtin_amdgcn_s_barrier();
        __builtin_amdgcn_sched_barrier(0);

        f32x16 acc[4];
        #pragma unroll
        for (int cb = 0; cb < 4; ++cb) acc[cb] = (f32x16)0.0f;

        // ---- K-loop with interleaved stores of prev row-block ----
        #pragma unroll
        for (int ks = 0; ks < 16; ++ks) {
            const ushort* bks = bbase + (size_t)ks * (SEQ * 16);
            short8 bv[4];
            #pragma unroll
            for (int cb = 0; cb < 4; ++cb)
                bv[cb] = *reinterpret_cast<const short8*>(bks + cb * 512);
            const short8 a = *reinterpret_cast<const short8*>(Ab + ks * 512 + pr6 * 8);
            #pragma unroll
            for (int cb = 0; cb < 4; ++cb)
                acc[cb] = __builtin_amdgcn_mfma_f32_32x32x16_bf16(a, bv[cb], acc[cb], 0, 0, 0);
            if (rb) {   // store row r=ks of prev block, all 4 col-chunks
                const int lrow = (ks & 3) + 8 * (ks >> 2) + 4 * hi;
                float* orow = outB + (size_t)(prev_base + lrow) * SEQ + colw + l31;
                #pragma unroll
                for (int cb = 0; cb < 4; ++cb) {
                    const uint32_t w = pk[cb][ks >> 1];
                    const float f = (ks & 1) ? __uint_as_float(w & 0xffff0000u)
                                             : __uint_as_float(w << 16);
                    __builtin_nontemporal_store(f, &orow[cb * 32]);
                }
            }
        }

        // ---- epilogue: exp(-dist/T), full-row sums (lgkm-only barriers) ----
        float part[16];
        #pragma unroll
        for (int r = 0; r < 16; ++r) {
            const float sqr = sqB[row_base + (r & 3) + 8 * (r >> 2) + 4 * hi];
            float p = 0.0f;
            #pragma unroll
            for (int cb = 0; cb < 4; ++cb) {
                const float e = exp2f((sqr + sqc[cb] - 2.0f * acc[cb][r]) * kC);
                acc[cb][r] = e;
                p += e;
            }
            part[r] = p;
        }
        #pragma unroll
        for (int r = 0; r < 16; ++r) {
            float p = part[r];
            p += __shfl_xor(p, 1);
            p += __shfl_xor(p, 2);
            p += __shfl_xor(p, 4);
            p += __shfl_xor(p, 8);
            p += __shfl_xor(p, 16);
            part[r] = p;
        }
        if (l31 == 0) {
            #pragma unroll
            for (int r = 0; r < 16; ++r) {
                const int lrow = (r & 3) + 8 * (r >> 2) + 4 * hi;
                red[lrow][wave] = part[r];
            }
        }
        asm volatile("" ::: "memory");
        asm volatile("s_waitcnt lgkmcnt(0)" ::: "memory");
        __builtin_amdgcn_sched_barrier(0);
        __builtin_amdgcn_s_barrier();
        asm volatile("" ::: "memory");
        if (tid < 32) {
            float s = 0.0f;
            #pragma unroll
            for (int w = 0; w < 16; ++w) s += red[tid][w];
            inv_s[tid] = 1.0f / s;
        }
        asm volatile("" ::: "memory");
        asm volatile("s_waitcnt lgkmcnt(0)" ::: "memory");
        __builtin_amdgcn_sched_barrier(0);
        __builtin_amdgcn_s_barrier();
        asm volatile("" ::: "memory");

        // ---- scale + pack to bf16 pairs (frees acc for next block) ----
        #pragma unroll
        for (int q = 0; q < 8; ++q) {
            const int re = 2 * q, ro = 2 * q + 1;
            const float se = inv_s[(re & 3) + 8 * (re >> 2) + 4 * hi];
            const float so = inv_s[(ro & 3) + 8 * (ro >> 2) + 4 * hi];
            #pragma unroll
            for (int cb = 0; cb < 4; ++cb)
                pk[cb][q] = cvt_pk_bf16(acc[cb][re] * se, acc[cb][ro] * so);
        }
        prev_base = row_base;
    }

    // ---- drain: stores of the last row-block ----
    #pragma unroll
    for (int ks = 0; ks < 16; ++ks) {
        const int lrow = (ks & 3) + 8 * (ks >> 2) + 4 * hi;
        float* orow = outB + (size_t)(prev_base + lrow) * SEQ + colw + l31;
        #pragma unroll
        for (int cb = 0; cb < 4; ++cb) {
            const uint32_t w = pk[cb][ks >> 1];
            const float f = (ks & 1) ? __uint_as_float(w & 0xffff0000u)
                                     : __uint_as_float(w << 16);
            __builtin_nontemporal_store(f, &orow[cb * 32]);
        }
    }
}

extern "C" void kernel_launch(void* const* d_in, const int* in_sizes, int n_in,
                              void* d_out, int out_size, void* d_ws, size_t ws_size,
                              hipStream_t stream) {
    (void)in_sizes; (void)n_in; (void)out_size; (void)ws_size;
    const float* x = (const float*)d_in[0];
    float* out = (float*)d_out;

    ushort* xb = (ushort*)d_ws;                                       // 16 MB bf16, k-major panels
    float*  sq = (float*)((char*)d_ws + (size_t)NB * SEQ * EDIM * 2); // 128 KB row norms

    prep_kernel<<<NB * SEQ / 4, 256, 0, stream>>>(x, xb, sq);

    dim3 grid(NB, 16);   // x = batch: flat%8 == batch%8 -> XCD locality; 256 WGs = 1/CU
    sims_main<<<grid, 1024, 0, stream>>>(xb, sq, out);
}

// Round 10
// 123.175 us; speedup vs baseline: 1.8491x; 1.8491x over previous
//
#include <hip/hip_runtime.h>
#include <hip/hip_bf16.h>

#define NB 16
#define SEQ 2048
#define EDIM 256

typedef __attribute__((ext_vector_type(16))) float f32x16;
typedef __attribute__((ext_vector_type(4)))  float f32x4;
typedef __attribute__((ext_vector_type(8)))  short short8;

static __device__ __forceinline__ ushort f2bf(float f) {
    uint32_t u = __float_as_uint(f);
    uint32_t r = (u + 0x7fffu + ((u >> 16) & 1u)) >> 16;
    return (ushort)r;
}
static __device__ __forceinline__ float bf2f(ushort h) {
    return __uint_as_float(((uint32_t)h) << 16);
}
// async global->LDS, 16 bytes per lane; LDS dest wave-uniform, global src per-lane.
static __device__ __forceinline__ void gll16(const ushort* g, ushort* l) {
    __builtin_amdgcn_global_load_lds(
        (const __attribute__((address_space(1))) uint32_t*)g,
        (__attribute__((address_space(3))) uint32_t*)l,
        16, 0, 0);
}

// Kernel 1: fp32 -> bf16 in K-MAJOR PANEL layout xb[b][ks][t][j] (ks=e>>4,
// j=e&15), plus per-row sum of squares of the bf16-rounded values (distance
// diagonal cancels exactly against the fp32-accumulated MFMA gram).
__global__ void prep_kernel(const float* __restrict__ x,
                            ushort* __restrict__ xb,
                            float* __restrict__ sq) {
    __shared__ ushort sh[4][256];
    const int tid  = threadIdx.x;
    const int r    = tid >> 6;
    const int lane = tid & 63;
    const int grow = blockIdx.x * 4;
    const int row  = grow + r;

    const f32x4* xp = reinterpret_cast<const f32x4*>(x + (size_t)row * EDIM + lane * 4);
    const f32x4 v = __builtin_nontemporal_load(xp);
    ushort h0 = f2bf(v.x), h1 = f2bf(v.y), h2 = f2bf(v.z), h3 = f2bf(v.w);
    ushort4 h; h.x = h0; h.y = h1; h.z = h2; h.w = h3;
    *reinterpret_cast<ushort4*>(&sh[r][lane * 4]) = h;

    const float fx = bf2f(h0), fy = bf2f(h1), fz = bf2f(h2), fw = bf2f(h3);
    float s = fx * fx + fy * fy + fz * fz + fw * fw;
    #pragma unroll
    for (int m = 1; m < 64; m <<= 1) s += __shfl_xor(s, m);
    if (lane == 0) sq[row] = s;

    __syncthreads();

    const int b   = grow >> 11;
    const int t0  = grow & 2047;
    const int ksx = tid >> 4;
    const int idx = tid & 15;
    const int r2  = idx >> 2;
    const int j   = (idx & 3) * 4;
    ushort4 o = *reinterpret_cast<ushort4*>(&sh[r2][ksx * 16 + j]);
    *reinterpret_cast<ushort4*>(xb + (size_t)b * SEQ * EDIM
                                   + (size_t)ksx * SEQ * 16
                                   + (size_t)(t0 + r2) * 16 + j) = o;
}

// Kernel 2: fused gram-GEMM + one-pass softmax (R7 structure, proven).
// WG = 1024 thr (16 waves), 32 rows x full 2048 cols; wave w owns cols
// [w*128,(w+1)*128). B fragments load directly from global (k-major panels,
// coalesced 1KB/wave-load) with an EXPLICIT 2-deep register pipeline
// (bv0/bv1 banks, load ks+2 after consuming ks) to hide L2 latency.
// A staged once to LDS (swizzled chunks, one barrier). Stores are a
// back-to-back nt burst in the epilogue (R8 lesson: never interleave
// streaming stores into a load-dependent loop -> sector RMW + vmcnt
// coupling; burst lets the coalescer form full lines).
__global__ __launch_bounds__(1024, 4) void sims_main(
        const ushort* __restrict__ xb,
        const float*  __restrict__ sq,
        float* __restrict__ out) {
    __shared__ __align__(16) ushort Ab[16 * 512];   // 16 KB: [ks][64 chunks][8]
    __shared__ float red[32][17];
    __shared__ float inv_s[32];

    const int b      = blockIdx.x;      // batch -> XCD = flat%8 = b%8
    const int rowblk = blockIdx.y;
    const int tid    = threadIdx.x;
    const int wave   = tid >> 6;        // 0..15
    const int lane   = tid & 63;
    const int l31    = lane & 31;
    const int hi     = lane >> 5;

    const int row_base = rowblk * 32;
    const ushort* xbB = xb + (size_t)b * SEQ * EDIM;

    // ---- stage A panel: wave w stages k-slice ks=w (1 KB); one barrier.
    {
        const int gl = lane ^ ((lane >> 3) & 7);    // src chunk (involution)
        gll16(xbB + (size_t)wave * (SEQ * 16) + (row_base + (gl >> 1)) * 16 + (gl & 1) * 8,
              Ab + wave * 512);
    }
    asm volatile("s_waitcnt vmcnt(0)" ::: "memory");
    __builtin_amdgcn_s_barrier();
    __builtin_amdgcn_sched_barrier(0);

    f32x16 acc[4];
    #pragma unroll
    for (int cb = 0; cb < 4; ++cb) acc[cb] = (f32x16)0.0f;

    const int r6  = l31 * 2 + hi;
    const int pr6 = r6 ^ ((r6 >> 3) & 7);           // swizzled A read chunk

    const int colw = wave * 128;
    const ushort* bbase = xbB + ((size_t)colw + l31) * 16 + hi * 8;

    // ---- K-loop: explicit 2-deep pipeline over k-slices ----
    short8 bv0[4], bv1[4];
    #pragma unroll
    for (int cb = 0; cb < 4; ++cb) {
        bv0[cb] = *reinterpret_cast<const short8*>(bbase + 0 * (SEQ * 16) + cb * 512);
        bv1[cb] = *reinterpret_cast<const short8*>(bbase + 1 * (SEQ * 16) + cb * 512);
    }

    #pragma unroll
    for (int kp = 0; kp < 8; ++kp) {
        const int ks0 = 2 * kp;
        const int ks1 = 2 * kp + 1;
        {
            const short8 a = *reinterpret_cast<const short8*>(Ab + ks0 * 512 + pr6 * 8);
            #pragma unroll
            for (int cb = 0; cb < 4; ++cb)
                acc[cb] = __builtin_amdgcn_mfma_f32_32x32x16_bf16(a, bv0[cb], acc[cb], 0, 0, 0);
            if (ks0 + 2 < 16) {
                #pragma unroll
                for (int cb = 0; cb < 4; ++cb)
                    bv0[cb] = *reinterpret_cast<const short8*>(
                        bbase + (size_t)(ks0 + 2) * (SEQ * 16) + cb * 512);
            }
        }
        {
            const short8 a = *reinterpret_cast<const short8*>(Ab + ks1 * 512 + pr6 * 8);
            #pragma unroll
            for (int cb = 0; cb < 4; ++cb)
                acc[cb] = __builtin_amdgcn_mfma_f32_32x32x16_bf16(a, bv1[cb], acc[cb], 0, 0, 0);
            if (ks1 + 2 < 16) {
                #pragma unroll
                for (int cb = 0; cb < 4; ++cb)
                    bv1[cb] = *reinterpret_cast<const short8*>(
                        bbase + (size_t)(ks1 + 2) * (SEQ * 16) + cb * 512);
            }
        }
    }

    // ---- epilogue: exp(-dist/T), full-row sums, scale, store ----
    constexpr float kC   = (float)(-1.4426950408889634 / 13.544);  // -log2(e)/T
    constexpr float m2kC = -2.0f * kC;
    const float* sqB = sq + b * SEQ;
    float kcc[4];
    #pragma unroll
    for (int cb = 0; cb < 4; ++cb) kcc[cb] = kC * sqB[colw + cb * 32 + l31];

    float part[16];
    #pragma unroll
    for (int r = 0; r < 16; ++r) {
        const float kcr = kC * sqB[row_base + (r & 3) + 8 * (r >> 2) + 4 * hi];
        float p = 0.0f;
        #pragma unroll
        for (int cb = 0; cb < 4; ++cb) {
            const float e = exp2f(fmaf(m2kC, acc[cb][r], kcr + kcc[cb]));
            acc[cb][r] = e;
            p += e;
        }
        part[r] = p;
    }
    #pragma unroll
    for (int r = 0; r < 16; ++r) {
        float p = part[r];
        p += __shfl_xor(p, 1);
        p += __shfl_xor(p, 2);
        p += __shfl_xor(p, 4);
        p += __shfl_xor(p, 8);
        p += __shfl_xor(p, 16);
        part[r] = p;
    }

    if (l31 == 0) {                      // lanes 0 and 32 of each wave
        #pragma unroll
        for (int r = 0; r < 16; ++r) {
            const int lrow = (r & 3) + 8 * (r >> 2) + 4 * hi;
            red[lrow][wave] = part[r];
        }
    }
    __syncthreads();
    if (tid < 32) {
        float s = 0.0f;
        #pragma unroll
        for (int w = 0; w < 16; ++w) s += red[tid][w];
        inv_s[tid] = 1.0f / s;
    }
    __syncthreads();

    float* outB = out + (size_t)b * SEQ * SEQ;
    #pragma unroll
    for (int r = 0; r < 16; ++r) {
        const int lrow = (r & 3) + 8 * (r >> 2) + 4 * hi;
        const float scale = inv_s[lrow];
        float* orow = outB + (size_t)(row_base + lrow) * SEQ + colw + l31;
        #pragma unroll
        for (int cb = 0; cb < 4; ++cb) {
            __builtin_nontemporal_store(acc[cb][r] * scale, &orow[cb * 32]);
        }
    }
}

extern "C" void kernel_launch(void* const* d_in, const int* in_sizes, int n_in,
                              void* d_out, int out_size, void* d_ws, size_t ws_size,
                              hipStream_t stream) {
    (void)in_sizes; (void)n_in; (void)out_size; (void)ws_size;
    const float* x = (const float*)d_in[0];
    float* out = (float*)d_out;

    ushort* xb = (ushort*)d_ws;                                       // 16 MB bf16, k-major panels
    float*  sq = (float*)((char*)d_ws + (size_t)NB * SEQ * EDIM * 2); // 128 KB row norms

    prep_kernel<<<NB * SEQ / 4, 256, 0, stream>>>(x, xb, sq);

    dim3 grid(NB, SEQ / 32);   // x = batch: flat%8 == batch%8 -> XCD locality
    sims_main<<<grid, 1024, 0, stream>>>(xb, sq, out);
}

// Round 11
// 122.108 us; speedup vs baseline: 1.8652x; 1.0087x over previous
//
#include <hip/hip_runtime.h>
#include <hip/hip_bf16.h>

#define NB 16
#define SEQ 2048
#define EDIM 256

typedef __attribute__((ext_vector_type(16))) float f32x16;
typedef __attribute__((ext_vector_type(4)))  float f32x4;
typedef __attribute__((ext_vector_type(8)))  short short8;

static __device__ __forceinline__ ushort f2bf(float f) {
    uint32_t u = __float_as_uint(f);
    uint32_t r = (u + 0x7fffu + ((u >> 16) & 1u)) >> 16;
    return (ushort)r;
}
static __device__ __forceinline__ float bf2f(ushort h) {
    return __uint_as_float(((uint32_t)h) << 16);
}
// async global->LDS, 16 bytes per lane; LDS dest wave-uniform, global src per-lane.
static __device__ __forceinline__ void gll16(const ushort* g, ushort* l) {
    __builtin_amdgcn_global_load_lds(
        (const __attribute__((address_space(1))) uint32_t*)g,
        (__attribute__((address_space(3))) uint32_t*)l,
        16, 0, 0);
}

// Kernel 1: fp32 -> bf16 in K-MAJOR PANEL layout xb[b][ks][t][j] (ks=e>>4,
// j=e&15), plus per-row sum of squares of the bf16-rounded values (distance
// diagonal cancels exactly against the fp32-accumulated MFMA gram).
__global__ void prep_kernel(const float* __restrict__ x,
                            ushort* __restrict__ xb,
                            float* __restrict__ sq) {
    __shared__ ushort sh[4][256];
    const int tid  = threadIdx.x;
    const int r    = tid >> 6;
    const int lane = tid & 63;
    const int grow = blockIdx.x * 4;
    const int row  = grow + r;

    const f32x4* xp = reinterpret_cast<const f32x4*>(x + (size_t)row * EDIM + lane * 4);
    const f32x4 v = __builtin_nontemporal_load(xp);
    ushort h0 = f2bf(v.x), h1 = f2bf(v.y), h2 = f2bf(v.z), h3 = f2bf(v.w);
    ushort4 h; h.x = h0; h.y = h1; h.z = h2; h.w = h3;
    *reinterpret_cast<ushort4*>(&sh[r][lane * 4]) = h;

    const float fx = bf2f(h0), fy = bf2f(h1), fz = bf2f(h2), fw = bf2f(h3);
    float s = fx * fx + fy * fy + fz * fz + fw * fw;
    #pragma unroll
    for (int m = 1; m < 64; m <<= 1) s += __shfl_xor(s, m);
    if (lane == 0) sq[row] = s;

    __syncthreads();

    const int b   = grow >> 11;
    const int t0  = grow & 2047;
    const int ksx = tid >> 4;
    const int idx = tid & 15;
    const int r2  = idx >> 2;
    const int j   = (idx & 3) * 4;
    ushort4 o = *reinterpret_cast<ushort4*>(&sh[r2][ksx * 16 + j]);
    *reinterpret_cast<ushort4*>(xb + (size_t)b * SEQ * EDIM
                                   + (size_t)ksx * SEQ * 16
                                   + (size_t)(t0 + r2) * 16 + j) = o;
}

// Kernel 2: fused gram-GEMM + one-pass softmax (R7 structure) with an
// LDS-TRANSPOSE BURST epilogue. The MFMA layout leaves each output row
// scattered over 16 waves as 128B chunks; storing that directly = random
// 128B HBM writes (~3.5 TB/s, the R7/R9 limiter). Instead: 4 chunks of
// 8 rows go through a 64KB LDS buffer; each wave then owns half a row and
// writes it as 4x dwordx4 nt stores, each instruction covering 1KB
// contiguous, each WG writing dense 64KB regions. Intra-chunk barriers are
// raw s_barrier + lgkmcnt-only (never vmcnt(0): don't drain nt stores).
__global__ __launch_bounds__(1024, 4) void sims_main(
        const ushort* __restrict__ xb,
        const float*  __restrict__ sq,
        float* __restrict__ out) {
    __shared__ __align__(16) ushort Ab[16 * 512];   // 16 KB: [ks][64 chunks][8]
    __shared__ __align__(16) float Tr[8][2048];     // 64 KB transpose buffer
    __shared__ float red[32][17];
    __shared__ float inv_s[32];

    const int b      = blockIdx.x;      // batch -> XCD = flat%8 = b%8
    const int rowblk = blockIdx.y;
    const int tid    = threadIdx.x;
    const int wave   = tid >> 6;        // 0..15
    const int lane   = tid & 63;
    const int l31    = lane & 31;
    const int hi     = lane >> 5;

    const int row_base = rowblk * 32;
    const ushort* xbB = xb + (size_t)b * SEQ * EDIM;

    // ---- stage A panel: wave w stages k-slice ks=w (1 KB); one barrier.
    {
        const int gl = lane ^ ((lane >> 3) & 7);    // src chunk (involution)
        gll16(xbB + (size_t)wave * (SEQ * 16) + (row_base + (gl >> 1)) * 16 + (gl & 1) * 8,
              Ab + wave * 512);
    }
    asm volatile("s_waitcnt vmcnt(0)" ::: "memory");
    __builtin_amdgcn_s_barrier();
    __builtin_amdgcn_sched_barrier(0);

    f32x16 acc[4];
    #pragma unroll
    for (int cb = 0; cb < 4; ++cb) acc[cb] = (f32x16)0.0f;

    const int r6  = l31 * 2 + hi;
    const int pr6 = r6 ^ ((r6 >> 3) & 7);           // swizzled A read chunk

    const int colw = wave * 128;
    const ushort* bbase = xbB + ((size_t)colw + l31) * 16 + hi * 8;

    #pragma unroll 2
    for (int ks = 0; ks < 16; ++ks) {
        const ushort* bks = bbase + (size_t)ks * (SEQ * 16);
        short8 bv[4];
        #pragma unroll
        for (int cb = 0; cb < 4; ++cb)
            bv[cb] = *reinterpret_cast<const short8*>(bks + cb * 512);
        const short8 a = *reinterpret_cast<const short8*>(Ab + ks * 512 + pr6 * 8);
        #pragma unroll
        for (int cb = 0; cb < 4; ++cb)
            acc[cb] = __builtin_amdgcn_mfma_f32_32x32x16_bf16(a, bv[cb], acc[cb], 0, 0, 0);
    }

    // ---- epilogue: exp(-dist/T), full-row sums ----
    constexpr float kC   = (float)(-1.4426950408889634 / 13.544);  // -log2(e)/T
    constexpr float m2kC = -2.0f * kC;
    const float* sqB = sq + b * SEQ;
    float kcc[4];
    #pragma unroll
    for (int cb = 0; cb < 4; ++cb) kcc[cb] = kC * sqB[colw + cb * 32 + l31];

    float part[16];
    #pragma unroll
    for (int r = 0; r < 16; ++r) {
        const float kcr = kC * sqB[row_base + (r & 3) + 8 * (r >> 2) + 4 * hi];
        float p = 0.0f;
        #pragma unroll
        for (int cb = 0; cb < 4; ++cb) {
            const float e = exp2f(fmaf(m2kC, acc[cb][r], kcr + kcc[cb]));
            acc[cb][r] = e;
            p += e;
        }
        part[r] = p;
    }
    #pragma unroll
    for (int r = 0; r < 16; ++r) {
        float p = part[r];
        p += __shfl_xor(p, 1);
        p += __shfl_xor(p, 2);
        p += __shfl_xor(p, 4);
        p += __shfl_xor(p, 8);
        p += __shfl_xor(p, 16);
        part[r] = p;
    }

    if (l31 == 0) {                      // lanes 0 and 32 of each wave
        #pragma unroll
        for (int r = 0; r < 16; ++r) {
            const int lrow = (r & 3) + 8 * (r >> 2) + 4 * hi;
            red[lrow][wave] = part[r];
        }
    }
    __syncthreads();                     // no stores in flight yet: safe
    if (tid < 32) {
        float s = 0.0f;
        #pragma unroll
        for (int w = 0; w < 16; ++w) s += red[tid][w];
        inv_s[tid] = 1.0f / s;
    }
    __syncthreads();

    // ---- transpose-burst store: 4 chunks x 8 rows through LDS ----
    float* outB = out + (size_t)b * SEQ * SEQ;
    const int lr8r = wave >> 1;          // row within chunk this wave stores
    const int half = wave & 1;           // which 4KB half of the row

    #pragma unroll 1
    for (int c = 0; c < 4; ++c) {
        // deposit rows r = 4c..4c+3 (both hi halves) into Tr
        #pragma unroll
        for (int rr = 0; rr < 4; ++rr) {
            const int r    = 4 * c + rr;
            const int lrow = rr + 8 * c + 4 * hi;    // global row offset
            const int lr8  = rr + 4 * hi;            // row within chunk
            const float scale = inv_s[lrow];
            #pragma unroll
            for (int cb = 0; cb < 4; ++cb)
                Tr[lr8][colw + cb * 32 + l31] = acc[cb][r] * scale;
        }
        asm volatile("s_waitcnt lgkmcnt(0)" ::: "memory");
        __builtin_amdgcn_sched_barrier(0);
        __builtin_amdgcn_s_barrier();
        asm volatile("" ::: "memory");

        // each wave reads half a row contiguously and bursts it out
        float* orow = outB + (size_t)(row_base + 8 * c + lr8r) * SEQ + half * 1024;
        #pragma unroll
        for (int j = 0; j < 4; ++j) {
            const f32x4 v = *reinterpret_cast<const f32x4*>(
                &Tr[lr8r][half * 1024 + j * 256 + lane * 4]);
            __builtin_nontemporal_store(v, reinterpret_cast<f32x4*>(&orow[j * 256 + lane * 4]));
        }
        asm volatile("s_waitcnt lgkmcnt(0)" ::: "memory");   // reads done (not stores)
        __builtin_amdgcn_sched_barrier(0);
        __builtin_amdgcn_s_barrier();
        asm volatile("" ::: "memory");
    }
}

extern "C" void kernel_launch(void* const* d_in, const int* in_sizes, int n_in,
                              void* d_out, int out_size, void* d_ws, size_t ws_size,
                              hipStream_t stream) {
    (void)in_sizes; (void)n_in; (void)out_size; (void)ws_size;
    const float* x = (const float*)d_in[0];
    float* out = (float*)d_out;

    ushort* xb = (ushort*)d_ws;                                       // 16 MB bf16, k-major panels
    float*  sq = (float*)((char*)d_ws + (size_t)NB * SEQ * EDIM * 2); // 128 KB row norms

    prep_kernel<<<NB * SEQ / 4, 256, 0, stream>>>(x, xb, sq);

    dim3 grid(NB, SEQ / 32);   // x = batch: flat%8 == batch%8 -> XCD locality
    sims_main<<<grid, 1024, 0, stream>>>(xb, sq, out);
}

// Round 12
// 121.296 us; speedup vs baseline: 1.8777x; 1.0067x over previous
//
#include <hip/hip_runtime.h>
#include <hip/hip_bf16.h>

#define NB 16
#define SEQ 2048
#define EDIM 256

typedef __attribute__((ext_vector_type(16))) float f32x16;
typedef __attribute__((ext_vector_type(4)))  float f32x4;
typedef __attribute__((ext_vector_type(8)))  short short8;

static __device__ __forceinline__ ushort f2bf(float f) {
    uint32_t u = __float_as_uint(f);
    uint32_t r = (u + 0x7fffu + ((u >> 16) & 1u)) >> 16;
    return (ushort)r;
}
static __device__ __forceinline__ float bf2f(ushort h) {
    return __uint_as_float(((uint32_t)h) << 16);
}
// async global->LDS, 16 bytes per lane; LDS dest wave-uniform, global src per-lane.
static __device__ __forceinline__ void gll16(const ushort* g, ushort* l) {
    __builtin_amdgcn_global_load_lds(
        (const __attribute__((address_space(1))) uint32_t*)g,
        (__attribute__((address_space(3))) uint32_t*)l,
        16, 0, 0);
}
// raw barrier: lgkm-only wait, never drains in-flight vmem stores
static __device__ __forceinline__ void lgkm_barrier() {
    asm volatile("s_waitcnt lgkmcnt(0)" ::: "memory");
    __builtin_amdgcn_sched_barrier(0);
    __builtin_amdgcn_s_barrier();
    asm volatile("" ::: "memory");
}

// Kernel 1: fp32 -> bf16 in K-MAJOR PANEL layout xb[b][ks][t][j] (ks=e>>4,
// j=e&15), plus per-row sum of squares of the bf16-rounded values (distance
// diagonal cancels exactly against the fp32-accumulated MFMA gram).
__global__ void prep_kernel(const float* __restrict__ x,
                            ushort* __restrict__ xb,
                            float* __restrict__ sq) {
    __shared__ ushort sh[4][256];
    const int tid  = threadIdx.x;
    const int r    = tid >> 6;
    const int lane = tid & 63;
    const int grow = blockIdx.x * 4;
    const int row  = grow + r;

    const f32x4* xp = reinterpret_cast<const f32x4*>(x + (size_t)row * EDIM + lane * 4);
    const f32x4 v = __builtin_nontemporal_load(xp);
    ushort h0 = f2bf(v.x), h1 = f2bf(v.y), h2 = f2bf(v.z), h3 = f2bf(v.w);
    ushort4 h; h.x = h0; h.y = h1; h.z = h2; h.w = h3;
    *reinterpret_cast<ushort4*>(&sh[r][lane * 4]) = h;

    const float fx = bf2f(h0), fy = bf2f(h1), fz = bf2f(h2), fw = bf2f(h3);
    float s = fx * fx + fy * fy + fz * fz + fw * fw;
    #pragma unroll
    for (int m = 1; m < 64; m <<= 1) s += __shfl_xor(s, m);
    if (lane == 0) sq[row] = s;

    __syncthreads();

    const int b   = grow >> 11;
    const int t0  = grow & 2047;
    const int ksx = tid >> 4;
    const int idx = tid & 15;
    const int r2  = idx >> 2;
    const int j   = (idx & 3) * 4;
    ushort4 o = *reinterpret_cast<ushort4*>(&sh[r2][ksx * 16 + j]);
    *reinterpret_cast<ushort4*>(xb + (size_t)b * SEQ * EDIM
                                   + (size_t)ksx * SEQ * 16
                                   + (size_t)(t0 + r2) * 16 + j) = o;
}

// Kernel 2: fused gram-GEMM + one-pass softmax, 4 ROW-BLOCKS PER WG with
// explicit store/compute overlap. Grid (16,16) = 256 WGs = 1/CU. Per WG,
// row-block i's 16 nt-store instructions stay in flight while row-block
// i+1's GEMM runs: the row-block-start wait is a counted vmcnt(16) (gfx9
// vmcnt retires in program order, so <=16 outstanding => the older A-panel
// gll16 prefetch has landed), and all other barriers are lgkm-only.
// A-panel double-buffered in LDS, prefetched right after the K-loop that
// frees it. Output goes through a 64KB LDS transpose so each store
// instruction covers 1KB contiguous (16 stores/wave/row-block).
__global__ __launch_bounds__(1024, 4) void sims_main(
        const ushort* __restrict__ xb,
        const float*  __restrict__ sq,
        float* __restrict__ out) {
    __shared__ __align__(16) ushort Ab[2][16 * 512];  // 32 KB dbuf A panels
    __shared__ __align__(16) float Tr[8][2048];       // 64 KB transpose buffer
    __shared__ float red[32][17];
    __shared__ float inv_s[32];

    const int b    = blockIdx.x;        // batch -> XCD = flat%8 = b%8
    const int g    = blockIdx.y;        // row-block group: rows [g*128,(g+1)*128)
    const int tid  = threadIdx.x;
    const int wave = tid >> 6;          // 0..15
    const int lane = tid & 63;
    const int l31  = lane & 31;
    const int hi   = lane >> 5;

    const ushort* xbB = xb + (size_t)b * SEQ * EDIM;
    const float*  sqB = sq + b * SEQ;
    float* outB = out + (size_t)b * SEQ * SEQ;

    const int colw = wave * 128;
    const ushort* bbase = xbB + ((size_t)colw + l31) * 16 + hi * 8;
    const int gl  = lane ^ ((lane >> 3) & 7);       // A-stage src chunk swizzle
    const int r6  = l31 * 2 + hi;
    const int pr6 = r6 ^ ((r6 >> 3) & 7);           // swizzled A read chunk

    constexpr float kC   = (float)(-1.4426950408889634 / 13.544);  // -log2(e)/T
    constexpr float m2kC = -2.0f * kC;
    float kcc[4];
    #pragma unroll
    for (int cb = 0; cb < 4; ++cb) kcc[cb] = kC * sqB[colw + cb * 32 + l31];

    // prologue: stage A panel for row-block 0
    gll16(xbB + (size_t)wave * (SEQ * 16) + ((g * 4 + 0) * 32 + (gl >> 1)) * 16 + (gl & 1) * 8,
          &Ab[0][wave * 512]);

    const int lr8r = wave >> 1;          // row within 8-row chunk this wave stores
    const int half = wave & 1;           // which 4KB half of the row

    #pragma unroll 1
    for (int rb = 0; rb < 4; ++rb) {
        // A-panel ready; prev row-block's <=16 stores may stay in flight.
        if (rb == 0) { asm volatile("s_waitcnt vmcnt(0)" ::: "memory"); }
        else         { asm volatile("s_waitcnt vmcnt(16)" ::: "memory"); }
        __builtin_amdgcn_sched_barrier(0);
        __builtin_amdgcn_s_barrier();
        __builtin_amdgcn_sched_barrier(0);

        const int row_base = (g * 4 + rb) * 32;
        const ushort* AbC = &Ab[rb & 1][0];

        f32x16 acc[4];
        #pragma unroll
        for (int cb = 0; cb < 4; ++cb) acc[cb] = (f32x16)0.0f;

        #pragma unroll 2
        for (int ks = 0; ks < 16; ++ks) {
            const ushort* bks = bbase + (size_t)ks * (SEQ * 16);
            short8 bv[4];
            #pragma unroll
            for (int cb = 0; cb < 4; ++cb)
                bv[cb] = *reinterpret_cast<const short8*>(bks + cb * 512);
            const short8 a = *reinterpret_cast<const short8*>(AbC + ks * 512 + pr6 * 8);
            #pragma unroll
            for (int cb = 0; cb < 4; ++cb)
                acc[cb] = __builtin_amdgcn_mfma_f32_32x32x16_bf16(a, bv[cb], acc[cb], 0, 0, 0);
        }

        // prefetch next row-block's A panel into the other buffer
        if (rb < 3) {
            gll16(xbB + (size_t)wave * (SEQ * 16)
                      + ((g * 4 + rb + 1) * 32 + (gl >> 1)) * 16 + (gl & 1) * 8,
                  &Ab[(rb + 1) & 1][wave * 512]);
        }

        // ---- epilogue: exp(-dist/T), full-row sums ----
        float part[16];
        #pragma unroll
        for (int r = 0; r < 16; ++r) {
            const float kcr = kC * sqB[row_base + (r & 3) + 8 * (r >> 2) + 4 * hi];
            float p = 0.0f;
            #pragma unroll
            for (int cb = 0; cb < 4; ++cb) {
                const float e = exp2f(fmaf(m2kC, acc[cb][r], kcr + kcc[cb]));
                acc[cb][r] = e;
                p += e;
            }
            part[r] = p;
        }
        #pragma unroll
        for (int r = 0; r < 16; ++r) {
            float p = part[r];
            p += __shfl_xor(p, 1);
            p += __shfl_xor(p, 2);
            p += __shfl_xor(p, 4);
            p += __shfl_xor(p, 8);
            p += __shfl_xor(p, 16);
            part[r] = p;
        }
        if (l31 == 0) {                  // lanes 0 and 32 of each wave
            #pragma unroll
            for (int r = 0; r < 16; ++r) {
                const int lrow = (r & 3) + 8 * (r >> 2) + 4 * hi;
                red[lrow][wave] = part[r];
            }
        }
        lgkm_barrier();
        if (tid < 32) {
            float s = 0.0f;
            #pragma unroll
            for (int w = 0; w < 16; ++w) s += red[tid][w];
            inv_s[tid] = 1.0f / s;
        }
        lgkm_barrier();

        // ---- transpose-burst store: 4 chunks x 8 rows through LDS ----
        #pragma unroll 1
        for (int c = 0; c < 4; ++c) {
            #pragma unroll
            for (int rr = 0; rr < 4; ++rr) {
                const int r    = 4 * c + rr;
                const int lrow = rr + 8 * c + 4 * hi;
                const int lr8  = rr + 4 * hi;
                const float scale = inv_s[lrow];
                #pragma unroll
                for (int cb = 0; cb < 4; ++cb)
                    Tr[lr8][colw + cb * 32 + l31] = acc[cb][r] * scale;
            }
            lgkm_barrier();
            float* orow = outB + (size_t)(row_base + 8 * c + lr8r) * SEQ + half * 1024;
            #pragma unroll
            for (int j = 0; j < 4; ++j) {
                const f32x4 v = *reinterpret_cast<const f32x4*>(
                    &Tr[lr8r][half * 1024 + j * 256 + lane * 4]);
                __builtin_nontemporal_store(v, reinterpret_cast<f32x4*>(&orow[j * 256 + lane * 4]));
            }
            lgkm_barrier();              // Tr reads complete; stores keep flying
        }
    }
}

extern "C" void kernel_launch(void* const* d_in, const int* in_sizes, int n_in,
                              void* d_out, int out_size, void* d_ws, size_t ws_size,
                              hipStream_t stream) {
    (void)in_sizes; (void)n_in; (void)out_size; (void)ws_size;
    const float* x = (const float*)d_in[0];
    float* out = (float*)d_out;

    ushort* xb = (ushort*)d_ws;                                       // 16 MB bf16, k-major panels
    float*  sq = (float*)((char*)d_ws + (size_t)NB * SEQ * EDIM * 2); // 128 KB row norms

    prep_kernel<<<NB * SEQ / 4, 256, 0, stream>>>(x, xb, sq);

    dim3 grid(NB, 16);   // x = batch: flat%8 == batch%8 -> XCD locality; 256 WGs = 1/CU
    sims_main<<<grid, 1024, 0, stream>>>(xb, sq, out);
}

// Round 13
// 112.912 us; speedup vs baseline: 2.0171x; 1.0743x over previous
//
#include <hip/hip_runtime.h>
#include <hip/hip_bf16.h>

#define NB 16
#define SEQ 2048
#define EDIM 256

typedef __attribute__((ext_vector_type(16))) float f32x16;
typedef __attribute__((ext_vector_type(4)))  float f32x4;
typedef __attribute__((ext_vector_type(8)))  short short8;

static __device__ __forceinline__ ushort f2bf(float f) {
    uint32_t u = __float_as_uint(f);
    uint32_t r = (u + 0x7fffu + ((u >> 16) & 1u)) >> 16;
    return (ushort)r;
}
static __device__ __forceinline__ float bf2f(ushort h) {
    return __uint_as_float(((uint32_t)h) << 16);
}
// async global->LDS, 16 bytes per lane; LDS dest wave-uniform, global src per-lane.
static __device__ __forceinline__ void gll16(const ushort* g, ushort* l) {
    __builtin_amdgcn_global_load_lds(
        (const __attribute__((address_space(1))) uint32_t*)g,
        (__attribute__((address_space(3))) uint32_t*)l,
        16, 0, 0);
}
// raw barrier: lgkm-only wait, never drains in-flight vmem stores
static __device__ __forceinline__ void lgkm_barrier() {
    asm volatile("s_waitcnt lgkmcnt(0)" ::: "memory");
    __builtin_amdgcn_sched_barrier(0);
    __builtin_amdgcn_s_barrier();
    asm volatile("" ::: "memory");
}

// Kernel 1: fp32 -> bf16 in K-MAJOR PANEL layout xb[b][ks][t][j] (ks=e>>4,
// j=e&15), plus per-row sum of squares of the bf16-rounded values (distance
// diagonal cancels exactly against the fp32-accumulated MFMA gram).
__global__ void prep_kernel(const float* __restrict__ x,
                            ushort* __restrict__ xb,
                            float* __restrict__ sq) {
    __shared__ ushort sh[4][256];
    const int tid  = threadIdx.x;
    const int r    = tid >> 6;
    const int lane = tid & 63;
    const int grow = blockIdx.x * 4;
    const int row  = grow + r;

    const f32x4* xp = reinterpret_cast<const f32x4*>(x + (size_t)row * EDIM + lane * 4);
    const f32x4 v = __builtin_nontemporal_load(xp);
    ushort h0 = f2bf(v.x), h1 = f2bf(v.y), h2 = f2bf(v.z), h3 = f2bf(v.w);
    ushort4 h; h.x = h0; h.y = h1; h.z = h2; h.w = h3;
    *reinterpret_cast<ushort4*>(&sh[r][lane * 4]) = h;

    const float fx = bf2f(h0), fy = bf2f(h1), fz = bf2f(h2), fw = bf2f(h3);
    float s = fx * fx + fy * fy + fz * fz + fw * fw;
    #pragma unroll
    for (int m = 1; m < 64; m <<= 1) s += __shfl_xor(s, m);
    if (lane == 0) sq[row] = s;

    __syncthreads();

    const int b   = grow >> 11;
    const int t0  = grow & 2047;
    const int ksx = tid >> 4;
    const int idx = tid & 15;
    const int r2  = idx >> 2;
    const int j   = (idx & 3) * 4;
    ushort4 o = *reinterpret_cast<ushort4*>(&sh[r2][ksx * 16 + j]);
    *reinterpret_cast<ushort4*>(xb + (size_t)b * SEQ * EDIM
                                   + (size_t)ksx * SEQ * 16
                                   + (size_t)(t0 + r2) * 16 + j) = o;
}

// Kernel 2: fused gram-GEMM + one-pass softmax, 4 row-blocks per WG
// (R11 structure). ONE CHANGE vs R11: output stores are PLAIN cached
// stores, not nontemporal. Evidence: harness fill kernel sustains
// 6.9 TB/s with plain stores at 10% occupancy; nt (no-allocate) stores
// bypass L2 write-back and backpressure waves at HBM rate, defeating
// the counted-vmcnt overlap. Plain stores retire into L2 dirty lines
// instantly and drain lazily under compute.
__global__ __launch_bounds__(1024, 4) void sims_main(
        const ushort* __restrict__ xb,
        const float*  __restrict__ sq,
        float* __restrict__ out) {
    __shared__ __align__(16) ushort Ab[2][16 * 512];  // 32 KB dbuf A panels
    __shared__ __align__(16) float Tr[8][2048];       // 64 KB transpose buffer
    __shared__ float red[32][17];
    __shared__ float inv_s[32];

    const int b    = blockIdx.x;        // batch -> XCD = flat%8 = b%8
    const int g    = blockIdx.y;        // row-block group: rows [g*128,(g+1)*128)
    const int tid  = threadIdx.x;
    const int wave = tid >> 6;          // 0..15
    const int lane = tid & 63;
    const int l31  = lane & 31;
    const int hi   = lane >> 5;

    const ushort* xbB = xb + (size_t)b * SEQ * EDIM;
    const float*  sqB = sq + b * SEQ;
    float* outB = out + (size_t)b * SEQ * SEQ;

    const int colw = wave * 128;
    const ushort* bbase = xbB + ((size_t)colw + l31) * 16 + hi * 8;
    const int gl  = lane ^ ((lane >> 3) & 7);       // A-stage src chunk swizzle
    const int r6  = l31 * 2 + hi;
    const int pr6 = r6 ^ ((r6 >> 3) & 7);           // swizzled A read chunk

    constexpr float kC   = (float)(-1.4426950408889634 / 13.544);  // -log2(e)/T
    constexpr float m2kC = -2.0f * kC;
    float kcc[4];
    #pragma unroll
    for (int cb = 0; cb < 4; ++cb) kcc[cb] = kC * sqB[colw + cb * 32 + l31];

    // prologue: stage A panel for row-block 0
    gll16(xbB + (size_t)wave * (SEQ * 16) + ((g * 4 + 0) * 32 + (gl >> 1)) * 16 + (gl & 1) * 8,
          &Ab[0][wave * 512]);

    const int lr8r = wave >> 1;          // row within 8-row chunk this wave stores
    const int half = wave & 1;           // which 4KB half of the row

    #pragma unroll 1
    for (int rb = 0; rb < 4; ++rb) {
        // A-panel ready; prev row-block's <=16 stores may stay in flight.
        if (rb == 0) { asm volatile("s_waitcnt vmcnt(0)" ::: "memory"); }
        else         { asm volatile("s_waitcnt vmcnt(16)" ::: "memory"); }
        __builtin_amdgcn_sched_barrier(0);
        __builtin_amdgcn_s_barrier();
        __builtin_amdgcn_sched_barrier(0);

        const int row_base = (g * 4 + rb) * 32;
        const ushort* AbC = &Ab[rb & 1][0];

        f32x16 acc[4];
        #pragma unroll
        for (int cb = 0; cb < 4; ++cb) acc[cb] = (f32x16)0.0f;

        #pragma unroll 2
        for (int ks = 0; ks < 16; ++ks) {
            const ushort* bks = bbase + (size_t)ks * (SEQ * 16);
            short8 bv[4];
            #pragma unroll
            for (int cb = 0; cb < 4; ++cb)
                bv[cb] = *reinterpret_cast<const short8*>(bks + cb * 512);
            const short8 a = *reinterpret_cast<const short8*>(AbC + ks * 512 + pr6 * 8);
            #pragma unroll
            for (int cb = 0; cb < 4; ++cb)
                acc[cb] = __builtin_amdgcn_mfma_f32_32x32x16_bf16(a, bv[cb], acc[cb], 0, 0, 0);
        }

        // prefetch next row-block's A panel into the other buffer
        if (rb < 3) {
            gll16(xbB + (size_t)wave * (SEQ * 16)
                      + ((g * 4 + rb + 1) * 32 + (gl >> 1)) * 16 + (gl & 1) * 8,
                  &Ab[(rb + 1) & 1][wave * 512]);
        }

        // ---- epilogue: exp(-dist/T), full-row sums ----
        float part[16];
        #pragma unroll
        for (int r = 0; r < 16; ++r) {
            const float kcr = kC * sqB[row_base + (r & 3) + 8 * (r >> 2) + 4 * hi];
            float p = 0.0f;
            #pragma unroll
            for (int cb = 0; cb < 4; ++cb) {
                const float e = exp2f(fmaf(m2kC, acc[cb][r], kcr + kcc[cb]));
                acc[cb][r] = e;
                p += e;
            }
            part[r] = p;
        }
        #pragma unroll
        for (int r = 0; r < 16; ++r) {
            float p = part[r];
            p += __shfl_xor(p, 1);
            p += __shfl_xor(p, 2);
            p += __shfl_xor(p, 4);
            p += __shfl_xor(p, 8);
            p += __shfl_xor(p, 16);
            part[r] = p;
        }
        if (l31 == 0) {                  // lanes 0 and 32 of each wave
            #pragma unroll
            for (int r = 0; r < 16; ++r) {
                const int lrow = (r & 3) + 8 * (r >> 2) + 4 * hi;
                red[lrow][wave] = part[r];
            }
        }
        lgkm_barrier();
        if (tid < 32) {
            float s = 0.0f;
            #pragma unroll
            for (int w = 0; w < 16; ++w) s += red[tid][w];
            inv_s[tid] = 1.0f / s;
        }
        lgkm_barrier();

        // ---- transpose-burst store: 4 chunks x 8 rows through LDS ----
        #pragma unroll 1
        for (int c = 0; c < 4; ++c) {
            #pragma unroll
            for (int rr = 0; rr < 4; ++rr) {
                const int r    = 4 * c + rr;
                const int lrow = rr + 8 * c + 4 * hi;
                const int lr8  = rr + 4 * hi;
                const float scale = inv_s[lrow];
                #pragma unroll
                for (int cb = 0; cb < 4; ++cb)
                    Tr[lr8][colw + cb * 32 + l31] = acc[cb][r] * scale;
            }
            lgkm_barrier();
            float* orow = outB + (size_t)(row_base + 8 * c + lr8r) * SEQ + half * 1024;
            #pragma unroll
            for (int j = 0; j < 4; ++j) {
                const f32x4 v = *reinterpret_cast<const f32x4*>(
                    &Tr[lr8r][half * 1024 + j * 256 + lane * 4]);
                *reinterpret_cast<f32x4*>(&orow[j * 256 + lane * 4]) = v;   // PLAIN store (the A/B)
            }
            lgkm_barrier();              // Tr reads complete; stores keep flying
        }
    }
}

extern "C" void kernel_launch(void* const* d_in, const int* in_sizes, int n_in,
                              void* d_out, int out_size, void* d_ws, size_t ws_size,
                              hipStream_t stream) {
    (void)in_sizes; (void)n_in; (void)out_size; (void)ws_size;
    const float* x = (const float*)d_in[0];
    float* out = (float*)d_out;

    ushort* xb = (ushort*)d_ws;                                       // 16 MB bf16, k-major panels
    float*  sq = (float*)((char*)d_ws + (size_t)NB * SEQ * EDIM * 2); // 128 KB row norms

    prep_kernel<<<NB * SEQ / 4, 256, 0, stream>>>(x, xb, sq);

    dim3 grid(NB, 16);   // x = batch: flat%8 == batch%8 -> XCD locality; 256 WGs = 1/CU
    sims_main<<<grid, 1024, 0, stream>>>(xb, sq, out);
}